// Round 2
// baseline (91.680 us; speedup 1.0000x reference)
//
#include <hip/hip_runtime.h>

typedef __attribute__((ext_vector_type(8))) short short8_t;      // 8 bf16 = MFMA A/B frag
typedef __attribute__((ext_vector_type(8))) unsigned short ushort8_t;
typedef __attribute__((ext_vector_type(4))) float float4_t;      // MFMA C/D frag

#define MFMA __builtin_amdgcn_mfma_f32_16x16x32_bf16

constexpr int BB   = 4;
constexpr int LL   = 2048;
constexpr int DM   = 1024;
constexpr int DK   = 128;
constexpr int MTOT = BB * LL;     // 8192
constexpr int MC   = 4;           // m-chunks in attention kernel
constexpr float INV2PI = 0.15915494309189535f;

__device__ __forceinline__ unsigned short f2bf(float f) {
    unsigned int u = __builtin_bit_cast(unsigned int, f);
    u += 0x7FFFu + ((u >> 16) & 1u);          // round-to-nearest-even
    return (unsigned short)(u >> 16);
}
__device__ __forceinline__ float bf2f(unsigned short h) {
    unsigned int u = ((unsigned int)h) << 16;
    return __builtin_bit_cast(float, u);
}

// ---------------------------------------------------------------------------
// K0: W [1024][128] f32  ->  W^T hi/lo bf16 [128][1024]  (LDS-tiled transpose)
// grid = 96 (32 k-tiles x 3 arrays), block = 256
// ---------------------------------------------------------------------------
__global__ __launch_bounds__(256) void k0_wsplit(
        const float* __restrict__ wq, const float* __restrict__ wk,
        const float* __restrict__ wv,
        unsigned short* __restrict__ wqh, unsigned short* __restrict__ wql,
        unsigned short* __restrict__ wkh, unsigned short* __restrict__ wkl,
        unsigned short* __restrict__ wvt) {
    int a  = blockIdx.x >> 5;     // 0:Wq 1:Wk 2:Wv
    int kt = blockIdx.x & 31;     // k-tile of 32
    const float* w = (a == 0) ? wq : (a == 1) ? wk : wv;
    __shared__ float tile[32][129];
    int t = threadIdx.x;
#pragma unroll
    for (int i = 0; i < 16; ++i) {
        int idx = t + i * 256;
        int kk = idx >> 7, n = idx & 127;
        tile[kk][n] = w[(kt * 32 + kk) * DK + n];      // coalesced read
    }
    __syncthreads();
#pragma unroll
    for (int i = 0; i < 16; ++i) {
        int idx = t + i * 256;
        int n = idx >> 5, kk = idx & 31;
        float f = tile[kk][n];
        unsigned short h = f2bf(f);
        int o = n * DM + kt * 32 + kk;                 // coalesced write
        if (a == 2) {
            wvt[o] = h;
        } else {
            unsigned short lo = f2bf(f - bf2f(h));
            if (a == 0) { wqh[o] = h; wql[o] = lo; }
            else        { wkh[o] = h; wkl[o] = lo; }
        }
    }
}

// ---------------------------------------------------------------------------
// K1: QKV projection.  x[8192][1024] f32 -> Qh/Ql/Kh/Kl/V bf16 [8192][128]
// Q,K use 3-term split bf16 (xh*wh + xh*wl + xl*wh); V plain bf16.
// grid = 256 (M-tile 32), block = 256 (4 waves, each 32 rows x 32 cols)
// ---------------------------------------------------------------------------
__global__ __launch_bounds__(256) void k1_proj(
        const float* __restrict__ x,
        const float* __restrict__ bq, const float* __restrict__ bk,
        const float* __restrict__ bv,
        const unsigned short* __restrict__ wqh, const unsigned short* __restrict__ wql,
        const unsigned short* __restrict__ wkh, const unsigned short* __restrict__ wkl,
        const unsigned short* __restrict__ wvt,
        unsigned short* __restrict__ qh, unsigned short* __restrict__ ql,
        unsigned short* __restrict__ kh, unsigned short* __restrict__ kl,
        unsigned short* __restrict__ vv) {
    int rowbase = blockIdx.x * 32;
    // pad rows to 40 bf16 (80 B): keeps ds_read_b128 16B-aligned, 2-way-free banks
    __shared__ __attribute__((aligned(16))) unsigned short xh[32 * 40];
    __shared__ __attribute__((aligned(16))) unsigned short xl[32 * 40];
    __shared__ __attribute__((aligned(16))) unsigned short wt[5][128 * 40];
    int t = threadIdx.x;
    int lane = t & 63, wid = t >> 6;
    int cc = lane & 15, g = lane >> 4;

    float4_t aq[2][2], ak[2][2], av[2][2];
#pragma unroll
    for (int rf = 0; rf < 2; ++rf)
#pragma unroll
        for (int cf = 0; cf < 2; ++cf) {
            aq[rf][cf] = (float4_t){0.f, 0.f, 0.f, 0.f};
            ak[rf][cf] = (float4_t){0.f, 0.f, 0.f, 0.f};
            av[rf][cf] = (float4_t){0.f, 0.f, 0.f, 0.f};
        }
    const unsigned short* wsrc[5] = {wqh, wql, wkh, wkl, wvt};

    for (int ks = 0; ks < 32; ++ks) {
        // stage x tile 32x32 (hi/lo split)
#pragma unroll
        for (int i = 0; i < 4; ++i) {
            int idx = t + i * 256;
            int r = idx >> 5, k = idx & 31;
            float f = x[(size_t)(rowbase + r) * DM + ks * 32 + k];
            unsigned short h = f2bf(f);
            xh[r * 40 + k] = h;
            xl[r * 40 + k] = f2bf(f - bf2f(h));
        }
        // stage 5 W^T tiles [128][32] (straight 16B copies, dst rows padded)
#pragma unroll
        for (int a = 0; a < 5; ++a) {
#pragma unroll
            for (int i = 0; i < 2; ++i) {
                int ci = t + i * 256;
                int r = ci >> 2, c4 = ci & 3;
                const short8_t* src =
                    (const short8_t*)(wsrc[a] + (size_t)r * DM + ks * 32 + c4 * 8);
                *(short8_t*)(&wt[a][r * 40 + c4 * 8]) = *src;
            }
        }
        __syncthreads();

        short8_t a_h[2], a_l[2];
#pragma unroll
        for (int rf = 0; rf < 2; ++rf) {
            a_h[rf] = *(const short8_t*)(&xh[(rf * 16 + cc) * 40 + g * 8]);
            a_l[rf] = *(const short8_t*)(&xl[(rf * 16 + cc) * 40 + g * 8]);
        }
#pragma unroll
        for (int cf = 0; cf < 2; ++cf) {
            int wr = (wid * 32 + cf * 16 + cc) * 40 + g * 8;
            short8_t bqh_ = *(const short8_t*)(&wt[0][wr]);
            short8_t bql_ = *(const short8_t*)(&wt[1][wr]);
            short8_t bkh_ = *(const short8_t*)(&wt[2][wr]);
            short8_t bkl_ = *(const short8_t*)(&wt[3][wr]);
            short8_t bv_  = *(const short8_t*)(&wt[4][wr]);
#pragma unroll
            for (int rf = 0; rf < 2; ++rf) {
                aq[rf][cf] = MFMA(a_h[rf], bqh_, aq[rf][cf], 0, 0, 0);
                aq[rf][cf] = MFMA(a_h[rf], bql_, aq[rf][cf], 0, 0, 0);
                aq[rf][cf] = MFMA(a_l[rf], bqh_, aq[rf][cf], 0, 0, 0);
                ak[rf][cf] = MFMA(a_h[rf], bkh_, ak[rf][cf], 0, 0, 0);
                ak[rf][cf] = MFMA(a_h[rf], bkl_, ak[rf][cf], 0, 0, 0);
                ak[rf][cf] = MFMA(a_l[rf], bkh_, ak[rf][cf], 0, 0, 0);
                av[rf][cf] = MFMA(a_h[rf], bv_,  av[rf][cf], 0, 0, 0);
            }
        }
        __syncthreads();
    }
    // epilogue: bias add, split-cast, store
#pragma unroll
    for (int rf = 0; rf < 2; ++rf)
#pragma unroll
        for (int cf = 0; cf < 2; ++cf) {
            int colg = wid * 32 + cf * 16 + cc;
            float bqv = bq[colg], bkv = bk[colg], bvv = bv[colg];
#pragma unroll
            for (int i = 0; i < 4; ++i) {
                int row = rowbase + rf * 16 + g * 4 + i;
                size_t o = (size_t)row * DK + colg;
                float q = aq[rf][cf][i] + bqv;
                unsigned short hq = f2bf(q);
                qh[o] = hq; ql[o] = f2bf(q - bf2f(hq));
                float kk2 = ak[rf][cf][i] + bkv;
                unsigned short hk = f2bf(kk2);
                kh[o] = hk; kl[o] = f2bf(kk2 - bf2f(hk));
                vv[o] = f2bf(av[rf][cf][i] + bvv);
            }
        }
}

// ---------------------------------------------------------------------------
// K2: out_partial = cos(Q K^T) V over one m-chunk of 512.
// grid = (MC=4, L/64=32, B=4), block = 256 (4 waves, each 16 q-rows)
// ---------------------------------------------------------------------------
__global__ __launch_bounds__(256) void k2_attn(
        const unsigned short* __restrict__ qh, const unsigned short* __restrict__ ql,
        const unsigned short* __restrict__ kh, const unsigned short* __restrict__ kl,
        const unsigned short* __restrict__ vv, float* __restrict__ part) {
    int mc = blockIdx.x, qt = blockIdx.y, b = blockIdx.z;
    int t = threadIdx.x, lane = t & 63, wid = t >> 6;
    int cc = lane & 15, g = lane >> 4;

    __shared__ __attribute__((aligned(16))) unsigned short khs[64 * 128]; // XOR-swizzled
    __shared__ __attribute__((aligned(16))) unsigned short kls[64 * 128]; // XOR-swizzled
    __shared__ __attribute__((aligned(16))) unsigned short vts[128 * 72]; // V^T, pad 72
    __shared__ __attribute__((aligned(16))) unsigned short ps[4][16 * 64]; // per-wave P

    int q0 = b * LL + qt * 64 + wid * 16;   // global row of this wave's Q block
    short8_t qhf[4], qlf[4];
#pragma unroll
    for (int s = 0; s < 4; ++s) {
        size_t off = (size_t)(q0 + cc) * DK + s * 32 + g * 8;
        qhf[s] = *(const short8_t*)(qh + off);
        qlf[s] = *(const short8_t*)(ql + off);
    }
    float4_t o[8];
#pragma unroll
    for (int cf = 0; cf < 8; ++cf) o[cf] = (float4_t){0.f, 0.f, 0.f, 0.f};

    for (int mi = 0; mi < 8; ++mi) {
        int mbase = b * LL + mc * 512 + mi * 64;
        // stage K hi/lo [64][128] with byte ^= (row&7)<<4 swizzle
        // FULL tile: 64 rows x 128 cols = 8192 bf16 each -> 4 sweeps of 256thr x 8
#pragma unroll
        for (int i = 0; i < 4; ++i) {
            int ci = t + i * 256;
            int r = ci >> 4, c8 = ci & 15;
            size_t src = (size_t)(mbase + r) * DK + c8 * 8;
            int dst = (r * 256 + c8 * 16) ^ ((r & 7) << 4);
            *(short8_t*)((char*)khs + dst) = *(const short8_t*)(kh + src);
            *(short8_t*)((char*)kls + dst) = *(const short8_t*)(kl + src);
        }
        // stage V^T [128 n][64 m] (pad 72)
#pragma unroll
        for (int i = 0; i < 4; ++i) {
            int ci = t + i * 256;
            int m = ci & 63, nb = ci >> 6;
            ushort8_t v8 = *(const ushort8_t*)(vv + (size_t)(mbase + m) * DK + nb * 8);
#pragma unroll
            for (int j = 0; j < 8; ++j) vts[(nb * 8 + j) * 72 + m] = v8[j];
        }
        __syncthreads();

        // S = Q K^T  (3-term split)
        float4_t sa[4];
#pragma unroll
        for (int cf = 0; cf < 4; ++cf) sa[cf] = (float4_t){0.f, 0.f, 0.f, 0.f};
#pragma unroll
        for (int cf = 0; cf < 4; ++cf) {
            int krow = cf * 16 + cc;
            int swz = (krow & 7) << 4;
#pragma unroll
            for (int s = 0; s < 4; ++s) {
                int off = (krow * 256 + (s * 32 + g * 8) * 2) ^ swz;
                short8_t bh = *(const short8_t*)((const char*)khs + off);
                short8_t bl = *(const short8_t*)((const char*)kls + off);
                sa[cf] = MFMA(qhf[s], bh, sa[cf], 0, 0, 0);
                sa[cf] = MFMA(qhf[s], bl, sa[cf], 0, 0, 0);
                sa[cf] = MFMA(qlf[s], bh, sa[cf], 0, 0, 0);
            }
        }
        // P = cos(S) -> per-wave swizzled LDS (bf16)
        char* pbase = (char*)&ps[wid][0];
#pragma unroll
        for (int cf = 0; cf < 4; ++cf) {
#pragma unroll
            for (int i = 0; i < 4; ++i) {
                float sv = sa[cf][i];
                float rv = sv * INV2PI;
                rv = rv - floorf(rv);            // [0,1) revolutions
                float cvv;
                asm volatile("v_cos_f32 %0, %1" : "=v"(cvv) : "v"(rv));
                int rr = g * 4 + i, c = cf * 16 + cc;
                int off = (rr * 128 + c * 2) ^ ((rr & 7) << 4);
                *(unsigned short*)(pbase + off) = f2bf(cvv);
            }
        }
        // out += P @ V   (plain bf16)
#pragma unroll
        for (int ksv = 0; ksv < 2; ++ksv) {
            int aoff = (cc * 128 + (ksv * 32 + g * 8) * 2) ^ ((cc & 7) << 4);
            short8_t pa = *(const short8_t*)(pbase + aoff);
#pragma unroll
            for (int cf = 0; cf < 8; ++cf) {
                short8_t vb = *(const short8_t*)(&vts[(cf * 16 + cc) * 72 + ksv * 32 + g * 8]);
                o[cf] = MFMA(pa, vb, o[cf], 0, 0, 0);
            }
        }
        __syncthreads();
    }
    // store fp32 partial: layout [MC][B][L][DK]
    float* pp = part + ((size_t)(mc * BB + b) * LL + qt * 64 + wid * 16) * DK;
#pragma unroll
    for (int cf = 0; cf < 8; ++cf)
#pragma unroll
        for (int i = 0; i < 4; ++i)
            pp[(g * 4 + i) * DK + cf * 16 + cc] = o[cf][i];
}

// ---------------------------------------------------------------------------
// K3: out = sum of MC partials
// ---------------------------------------------------------------------------
__global__ __launch_bounds__(256) void k3_reduce(const float4_t* __restrict__ part,
                                                 float4_t* __restrict__ out) {
    constexpr int NT4 = MTOT * DK / 4;   // 262144
    int idx = blockIdx.x * 256 + threadIdx.x;
    float4_t s = part[idx];
#pragma unroll
    for (int c = 1; c < MC; ++c) s += part[idx + (size_t)c * NT4];
    out[idx] = s;
}

// ---------------------------------------------------------------------------
extern "C" void kernel_launch(void* const* d_in, const int* in_sizes, int n_in,
                              void* d_out, int out_size, void* d_ws, size_t ws_size,
                              hipStream_t stream) {
    const float* x  = (const float*)d_in[0];
    const float* Wq = (const float*)d_in[1];
    const float* bq = (const float*)d_in[2];
    const float* Wk = (const float*)d_in[3];
    const float* bk = (const float*)d_in[4];
    const float* Wv = (const float*)d_in[5];
    const float* bv = (const float*)d_in[6];

    char* ws = (char*)d_ws;
    size_t off = 0;
    auto alloc = [&](size_t bytes) -> char* {
        char* p = ws + off;
        off += (bytes + 255) & ~(size_t)255;
        return p;
    };
    unsigned short* wqh = (unsigned short*)alloc((size_t)DK * DM * 2);
    unsigned short* wql = (unsigned short*)alloc((size_t)DK * DM * 2);
    unsigned short* wkh = (unsigned short*)alloc((size_t)DK * DM * 2);
    unsigned short* wkl = (unsigned short*)alloc((size_t)DK * DM * 2);
    unsigned short* wvt = (unsigned short*)alloc((size_t)DK * DM * 2);
    unsigned short* qh  = (unsigned short*)alloc((size_t)MTOT * DK * 2);
    unsigned short* ql  = (unsigned short*)alloc((size_t)MTOT * DK * 2);
    unsigned short* kh  = (unsigned short*)alloc((size_t)MTOT * DK * 2);
    unsigned short* kl  = (unsigned short*)alloc((size_t)MTOT * DK * 2);
    unsigned short* vv  = (unsigned short*)alloc((size_t)MTOT * DK * 2);
    float* part = (float*)alloc((size_t)MC * MTOT * DK * 4);

    k0_wsplit<<<96, 256, 0, stream>>>(Wq, Wk, Wv, wqh, wql, wkh, wkl, wvt);
    k1_proj<<<MTOT / 32, 256, 0, stream>>>(x, bq, bk, bv, wqh, wql, wkh, wkl, wvt,
                                           qh, ql, kh, kl, vv);
    k2_attn<<<dim3(MC, LL / 64, BB), 256, 0, stream>>>(qh, ql, kh, kl, vv, part);
    k3_reduce<<<(MTOT * DK / 4) / 256, 256, 0, stream>>>((const float4_t*)part,
                                                         (float4_t*)d_out);
}

// Round 3
// 81.982 us; speedup vs baseline: 1.1183x; 1.1183x over previous
//
#include <hip/hip_runtime.h>

typedef __attribute__((ext_vector_type(8))) short short8_t;      // 8 bf16 = MFMA A/B frag
typedef __attribute__((ext_vector_type(8))) unsigned short ushort8_t;
typedef __attribute__((ext_vector_type(4))) float float4_t;      // MFMA C/D frag

#define MFMA __builtin_amdgcn_mfma_f32_16x16x32_bf16

constexpr int BB   = 4;
constexpr int LL   = 2048;
constexpr int DM   = 1024;
constexpr int DK   = 128;
constexpr int MTOT = BB * LL;     // 8192
constexpr int MC   = 4;           // m-chunks in attention kernel
constexpr float INV2PI = 0.15915494309189535f;

__device__ __forceinline__ unsigned short f2bf(float f) {
    unsigned int u = __builtin_bit_cast(unsigned int, f);
    u += 0x7FFFu + ((u >> 16) & 1u);          // round-to-nearest-even
    return (unsigned short)(u >> 16);
}
__device__ __forceinline__ float bf2f(unsigned short h) {
    unsigned int u = ((unsigned int)h) << 16;
    return __builtin_bit_cast(float, u);
}

// ---------------------------------------------------------------------------
// K0: W [1024][128] f32  ->  W^T hi/lo bf16 [128][1024]  (LDS-tiled transpose)
// grid = 96 (32 k-tiles x 3 arrays), block = 256
// ---------------------------------------------------------------------------
__global__ __launch_bounds__(256) void k0_wsplit(
        const float* __restrict__ wq, const float* __restrict__ wk,
        const float* __restrict__ wv,
        unsigned short* __restrict__ wqh, unsigned short* __restrict__ wql,
        unsigned short* __restrict__ wkh, unsigned short* __restrict__ wkl,
        unsigned short* __restrict__ wvt) {
    int a  = blockIdx.x >> 5;     // 0:Wq 1:Wk 2:Wv
    int kt = blockIdx.x & 31;     // k-tile of 32
    const float* w = (a == 0) ? wq : (a == 1) ? wk : wv;
    __shared__ float tile[32][129];
    int t = threadIdx.x;
#pragma unroll
    for (int i = 0; i < 16; ++i) {
        int idx = t + i * 256;
        int kk = idx >> 7, n = idx & 127;
        tile[kk][n] = w[(kt * 32 + kk) * DK + n];      // coalesced read
    }
    __syncthreads();
#pragma unroll
    for (int i = 0; i < 16; ++i) {
        int idx = t + i * 256;
        int n = idx >> 5, kk = idx & 31;
        float f = tile[kk][n];
        unsigned short h = f2bf(f);
        int o = n * DM + kt * 32 + kk;                 // coalesced write
        if (a == 2) {
            wvt[o] = h;
        } else {
            unsigned short lo = f2bf(f - bf2f(h));
            if (a == 0) { wqh[o] = h; wql[o] = lo; }
            else        { wkh[o] = h; wkl[o] = lo; }
        }
    }
}

// ---------------------------------------------------------------------------
// K1 v2: QKV projection as 3 GEMM groups (grid.y: 0=Q, 1=K, 2=V).
// BM=64, BK=64, BN=128. block=256 (4 waves, 2x2 of 32x64). grid.x=128 M-tiles.
// 3 blocks/CU (48 KB LDS). All LDS tiles 16B-slot XOR-swizzled: slot ^= row&7.
// Q,K: 3-term split bf16 (xh*wh + xh*wl + xl*wh); V: plain bf16.
// ---------------------------------------------------------------------------
__global__ __launch_bounds__(256, 3) void k1_proj(
        const float* __restrict__ x,
        const float* __restrict__ bq, const float* __restrict__ bk,
        const float* __restrict__ bv,
        const unsigned short* __restrict__ wqh, const unsigned short* __restrict__ wql,
        const unsigned short* __restrict__ wkh, const unsigned short* __restrict__ wkl,
        const unsigned short* __restrict__ wvt,
        unsigned short* __restrict__ qh, unsigned short* __restrict__ ql,
        unsigned short* __restrict__ kh, unsigned short* __restrict__ kl,
        unsigned short* __restrict__ vv) {
    int mt  = blockIdx.x;          // M-tile of 64 rows
    int grp = blockIdx.y;          // 0:Q 1:K 2:V
    int rowbase = mt * 64;

    __shared__ __attribute__((aligned(16))) unsigned short xs[2][64 * 64];   // x hi/lo, rows 128B
    __shared__ __attribute__((aligned(16))) unsigned short wsm[2][128 * 64]; // W hi/lo, rows 128B

    int t = threadIdx.x, lane = t & 63, wid = t >> 6;
    int cc = lane & 15, g = lane >> 4;
    int wr = wid >> 1, wc = wid & 1;   // wave tile: rows wr*32, cols wc*64

    const unsigned short* b0 = (grp == 0) ? wqh : (grp == 1) ? wkh : wvt;
    const unsigned short* b1 = (grp == 0) ? wql : (grp == 1) ? wkl : wvt;
    const bool split = (grp < 2);

    float4_t acc[2][4];
#pragma unroll
    for (int rf = 0; rf < 2; ++rf)
#pragma unroll
        for (int cf = 0; cf < 4; ++cf) acc[rf][cf] = (float4_t){0.f, 0.f, 0.f, 0.f};

    // staging maps
    int ar = t >> 2, aq_ = t & 3;      // A: row, 16-float chunk
    int bc = t >> 1, bh = t & 1;       // B: row (W^T col), 64B half-row

#pragma unroll 1
    for (int ks = 0; ks < 16; ++ks) {
        int k0 = ks * 64;
        // ---- issue global loads (overlap with other waves' compute/barrier)
        const float4_t* xp = (const float4_t*)(x + (size_t)(rowbase + ar) * DM + k0 + aq_ * 16);
        float4_t xf[4];
#pragma unroll
        for (int j = 0; j < 4; ++j) xf[j] = xp[j];
        short8_t bfr0[4], bfr1[4];
#pragma unroll
        for (int jj = 0; jj < 4; ++jj) {
            bfr0[jj] = *(const short8_t*)(b0 + (size_t)bc * DM + k0 + (bh * 4 + jj) * 8);
            if (split)
                bfr1[jj] = *(const short8_t*)(b1 + (size_t)bc * DM + k0 + (bh * 4 + jj) * 8);
        }
        __syncthreads();   // previous compute done; LDS safe to overwrite

        // ---- A: convert 16 f32 -> hi/lo bf16, 2 b128 writes each (swizzled)
#pragma unroll
        for (int half = 0; half < 2; ++half) {
            short8_t hh, ll;
#pragma unroll
            for (int e = 0; e < 8; ++e) {
                float f = xf[half * 2 + (e >> 2)][e & 3];
                unsigned short h = f2bf(f);
                hh[e] = (short)h;
                ll[e] = (short)f2bf(f - bf2f(h));
            }
            int slot = (aq_ * 2 + half) ^ (ar & 7);
            *(short8_t*)((char*)xs[0] + ar * 128 + slot * 16) = hh;
            *(short8_t*)((char*)xs[1] + ar * 128 + slot * 16) = ll;
        }
        // ---- B: 4 b128 writes per array (swizzled)
#pragma unroll
        for (int jj = 0; jj < 4; ++jj) {
            int slot = (bh * 4 + jj) ^ (bc & 7);
            *(short8_t*)((char*)wsm[0] + bc * 128 + slot * 16) = bfr0[jj];
            if (split)
                *(short8_t*)((char*)wsm[1] + bc * 128 + slot * 16) = bfr1[jj];
        }
        __syncthreads();

        // ---- compute: 2 k-slices of 32
#pragma unroll
        for (int s = 0; s < 2; ++s) {
            short8_t a_h[2], a_l[2];
#pragma unroll
            for (int rf = 0; rf < 2; ++rf) {
                int r = wr * 32 + rf * 16 + cc;
                int slot = (s * 4 + g) ^ (r & 7);
                a_h[rf] = *(const short8_t*)((const char*)xs[0] + r * 128 + slot * 16);
                if (split)
                    a_l[rf] = *(const short8_t*)((const char*)xs[1] + r * 128 + slot * 16);
            }
#pragma unroll
            for (int cf = 0; cf < 4; ++cf) {
                int c = wc * 64 + cf * 16 + cc;
                int slot = (s * 4 + g) ^ (c & 7);
                short8_t b_h = *(const short8_t*)((const char*)wsm[0] + c * 128 + slot * 16);
#pragma unroll
                for (int rf = 0; rf < 2; ++rf)
                    acc[rf][cf] = MFMA(a_h[rf], b_h, acc[rf][cf], 0, 0, 0);
                if (split) {
                    short8_t b_l = *(const short8_t*)((const char*)wsm[1] + c * 128 + slot * 16);
#pragma unroll
                    for (int rf = 0; rf < 2; ++rf) {
                        acc[rf][cf] = MFMA(a_h[rf], b_l, acc[rf][cf], 0, 0, 0);
                        acc[rf][cf] = MFMA(a_l[rf], b_h, acc[rf][cf], 0, 0, 0);
                    }
                }
            }
        }
    }

    // ---- epilogue: bias, split-cast, store
    const float* bias = (grp == 0) ? bq : (grp == 1) ? bk : bv;
    unsigned short* oh = (grp == 0) ? qh : (grp == 1) ? kh : vv;
    unsigned short* ol = (grp == 0) ? ql : kl;   // unused for V
#pragma unroll
    for (int rf = 0; rf < 2; ++rf)
#pragma unroll
        for (int cf = 0; cf < 4; ++cf) {
            int col = wc * 64 + cf * 16 + cc;
            float bv_ = bias[col];
#pragma unroll
            for (int i = 0; i < 4; ++i) {
                int row = rowbase + wr * 32 + rf * 16 + g * 4 + i;
                size_t o = (size_t)row * DK + col;
                float v = acc[rf][cf][i] + bv_;
                unsigned short h = f2bf(v);
                oh[o] = h;
                if (split) ol[o] = f2bf(v - bf2f(h));
            }
        }
}

// ---------------------------------------------------------------------------
// K2: out_partial = cos(Q K^T) V over one m-chunk of 512.
// grid = (MC=4, L/64=32, B=4), block = 256 (4 waves, each 16 q-rows)
// ---------------------------------------------------------------------------
__global__ __launch_bounds__(256) void k2_attn(
        const unsigned short* __restrict__ qh, const unsigned short* __restrict__ ql,
        const unsigned short* __restrict__ kh, const unsigned short* __restrict__ kl,
        const unsigned short* __restrict__ vv, float* __restrict__ part) {
    int mc = blockIdx.x, qt = blockIdx.y, b = blockIdx.z;
    int t = threadIdx.x, lane = t & 63, wid = t >> 6;
    int cc = lane & 15, g = lane >> 4;

    __shared__ __attribute__((aligned(16))) unsigned short khs[64 * 128]; // XOR-swizzled
    __shared__ __attribute__((aligned(16))) unsigned short kls[64 * 128]; // XOR-swizzled
    __shared__ __attribute__((aligned(16))) unsigned short vts[128 * 72]; // V^T, pad 72
    __shared__ __attribute__((aligned(16))) unsigned short ps[4][16 * 64]; // per-wave P

    int q0 = b * LL + qt * 64 + wid * 16;   // global row of this wave's Q block
    short8_t qhf[4], qlf[4];
#pragma unroll
    for (int s = 0; s < 4; ++s) {
        size_t off = (size_t)(q0 + cc) * DK + s * 32 + g * 8;
        qhf[s] = *(const short8_t*)(qh + off);
        qlf[s] = *(const short8_t*)(ql + off);
    }
    float4_t o[8];
#pragma unroll
    for (int cf = 0; cf < 8; ++cf) o[cf] = (float4_t){0.f, 0.f, 0.f, 0.f};

    for (int mi = 0; mi < 8; ++mi) {
        int mbase = b * LL + mc * 512 + mi * 64;
        // stage K hi/lo [64][128] with byte ^= (row&7)<<4 swizzle
        // FULL tile: 64 rows x 128 cols = 8192 bf16 each -> 4 sweeps of 256thr x 8
#pragma unroll
        for (int i = 0; i < 4; ++i) {
            int ci = t + i * 256;
            int r = ci >> 4, c8 = ci & 15;
            size_t src = (size_t)(mbase + r) * DK + c8 * 8;
            int dst = (r * 256 + c8 * 16) ^ ((r & 7) << 4);
            *(short8_t*)((char*)khs + dst) = *(const short8_t*)(kh + src);
            *(short8_t*)((char*)kls + dst) = *(const short8_t*)(kl + src);
        }
        // stage V^T [128 n][64 m] (pad 72)
#pragma unroll
        for (int i = 0; i < 4; ++i) {
            int ci = t + i * 256;
            int m = ci & 63, nb = ci >> 6;
            ushort8_t v8 = *(const ushort8_t*)(vv + (size_t)(mbase + m) * DK + nb * 8);
#pragma unroll
            for (int j = 0; j < 8; ++j) vts[(nb * 8 + j) * 72 + m] = v8[j];
        }
        __syncthreads();

        // S = Q K^T  (3-term split)
        float4_t sa[4];
#pragma unroll
        for (int cf = 0; cf < 4; ++cf) sa[cf] = (float4_t){0.f, 0.f, 0.f, 0.f};
#pragma unroll
        for (int cf = 0; cf < 4; ++cf) {
            int krow = cf * 16 + cc;
            int swz = (krow & 7) << 4;
#pragma unroll
            for (int s = 0; s < 4; ++s) {
                int off = (krow * 256 + (s * 32 + g * 8) * 2) ^ swz;
                short8_t bh = *(const short8_t*)((const char*)khs + off);
                short8_t bl = *(const short8_t*)((const char*)kls + off);
                sa[cf] = MFMA(qhf[s], bh, sa[cf], 0, 0, 0);
                sa[cf] = MFMA(qhf[s], bl, sa[cf], 0, 0, 0);
                sa[cf] = MFMA(qlf[s], bh, sa[cf], 0, 0, 0);
            }
        }
        // P = cos(S) -> per-wave swizzled LDS (bf16)
        char* pbase = (char*)&ps[wid][0];
#pragma unroll
        for (int cf = 0; cf < 4; ++cf) {
#pragma unroll
            for (int i = 0; i < 4; ++i) {
                float sv = sa[cf][i];
                float rv = sv * INV2PI;
                rv = rv - floorf(rv);            // [0,1) revolutions
                float cvv;
                asm volatile("v_cos_f32 %0, %1" : "=v"(cvv) : "v"(rv));
                int rr = g * 4 + i, c = cf * 16 + cc;
                int off = (rr * 128 + c * 2) ^ ((rr & 7) << 4);
                *(unsigned short*)(pbase + off) = f2bf(cvv);
            }
        }
        // out += P @ V   (plain bf16)
#pragma unroll
        for (int ksv = 0; ksv < 2; ++ksv) {
            int aoff = (cc * 128 + (ksv * 32 + g * 8) * 2) ^ ((cc & 7) << 4);
            short8_t pa = *(const short8_t*)(pbase + aoff);
#pragma unroll
            for (int cf = 0; cf < 8; ++cf) {
                short8_t vb = *(const short8_t*)(&vts[(cf * 16 + cc) * 72 + ksv * 32 + g * 8]);
                o[cf] = MFMA(pa, vb, o[cf], 0, 0, 0);
            }
        }
        __syncthreads();
    }
    // store fp32 partial: layout [MC][B][L][DK]
    float* pp = part + ((size_t)(mc * BB + b) * LL + qt * 64 + wid * 16) * DK;
#pragma unroll
    for (int cf = 0; cf < 8; ++cf)
#pragma unroll
        for (int i = 0; i < 4; ++i)
            pp[(g * 4 + i) * DK + cf * 16 + cc] = o[cf][i];
}

// ---------------------------------------------------------------------------
// K3: out = sum of MC partials
// ---------------------------------------------------------------------------
__global__ __launch_bounds__(256) void k3_reduce(const float4_t* __restrict__ part,
                                                 float4_t* __restrict__ out) {
    constexpr int NT4 = MTOT * DK / 4;   // 262144
    int idx = blockIdx.x * 256 + threadIdx.x;
    float4_t s = part[idx];
#pragma unroll
    for (int c = 1; c < MC; ++c) s += part[idx + (size_t)c * NT4];
    out[idx] = s;
}

// ---------------------------------------------------------------------------
extern "C" void kernel_launch(void* const* d_in, const int* in_sizes, int n_in,
                              void* d_out, int out_size, void* d_ws, size_t ws_size,
                              hipStream_t stream) {
    const float* x  = (const float*)d_in[0];
    const float* Wq = (const float*)d_in[1];
    const float* bq = (const float*)d_in[2];
    const float* Wk = (const float*)d_in[3];
    const float* bk = (const float*)d_in[4];
    const float* Wv = (const float*)d_in[5];
    const float* bv = (const float*)d_in[6];

    char* ws = (char*)d_ws;
    size_t off = 0;
    auto alloc = [&](size_t bytes) -> char* {
        char* p = ws + off;
        off += (bytes + 255) & ~(size_t)255;
        return p;
    };
    unsigned short* wqh = (unsigned short*)alloc((size_t)DK * DM * 2);
    unsigned short* wql = (unsigned short*)alloc((size_t)DK * DM * 2);
    unsigned short* wkh = (unsigned short*)alloc((size_t)DK * DM * 2);
    unsigned short* wkl = (unsigned short*)alloc((size_t)DK * DM * 2);
    unsigned short* wvt = (unsigned short*)alloc((size_t)DK * DM * 2);
    unsigned short* qh  = (unsigned short*)alloc((size_t)MTOT * DK * 2);
    unsigned short* ql  = (unsigned short*)alloc((size_t)MTOT * DK * 2);
    unsigned short* kh  = (unsigned short*)alloc((size_t)MTOT * DK * 2);
    unsigned short* kl  = (unsigned short*)alloc((size_t)MTOT * DK * 2);
    unsigned short* vv  = (unsigned short*)alloc((size_t)MTOT * DK * 2);
    float* part = (float*)alloc((size_t)MC * MTOT * DK * 4);

    k0_wsplit<<<96, 256, 0, stream>>>(Wq, Wk, Wv, wqh, wql, wkh, wkl, wvt);
    k1_proj<<<dim3(MTOT / 64, 3), 256, 0, stream>>>(x, bq, bk, bv,
                                                    wqh, wql, wkh, wkl, wvt,
                                                    qh, ql, kh, kl, vv);
    k2_attn<<<dim3(MC, LL / 64, BB), 256, 0, stream>>>(qh, ql, kh, kl, vv, part);
    k3_reduce<<<(MTOT * DK / 4) / 256, 256, 0, stream>>>((const float4_t*)part,
                                                         (float4_t*)d_out);
}

// Round 4
// 74.750 us; speedup vs baseline: 1.2265x; 1.0967x over previous
//
#include <hip/hip_runtime.h>

typedef __attribute__((ext_vector_type(8))) short short8_t;      // 8 bf16
typedef __attribute__((ext_vector_type(4))) float float4_t;      // MFMA C/D frag

#define MFMA __builtin_amdgcn_mfma_f32_16x16x32_bf16

constexpr int BB   = 4;
constexpr int LL   = 2048;
constexpr int DM   = 1024;
constexpr int DK   = 128;
constexpr int MTOT = BB * LL;     // 8192
constexpr int MC   = 4;
constexpr float INV2PI = 0.15915494309189535f;

__device__ __forceinline__ unsigned short f2bf(float f) {
    unsigned int u = __builtin_bit_cast(unsigned int, f);
    u += 0x7FFFu + ((u >> 16) & 1u);          // RNE
    return (unsigned short)(u >> 16);
}
__device__ __forceinline__ float bf2f(unsigned short h) {
    unsigned int u = ((unsigned int)h) << 16;
    return __builtin_bit_cast(float, u);
}
// async global->LDS, 16B per lane; lds ptr must be wave-uniform
__device__ __forceinline__ void gload16(const void* g, void* l) {
    __builtin_amdgcn_global_load_lds(
        (const __attribute__((address_space(1))) void*)g,
        (__attribute__((address_space(3))) void*)l, 16, 0, 0);
}

// ---------------------------------------------------------------------------
// K0: W [1024 k][128 n] f32 -> W^T hi/lo bf16 as SWIZZLED TILE IMAGES for
// gload_lds: per kc (64-k chunk): [128 n][16 slots], element (n,kk) at short
// offset kc*8192 + n*64 + ((kk>>3)^(n&7))*8 + (kk&7).
// grid (16 kc, 3 array), block 256.
// ---------------------------------------------------------------------------
__global__ __launch_bounds__(256) void k0_wsplit(
        const float* __restrict__ wq, const float* __restrict__ wk,
        const float* __restrict__ wv,
        unsigned short* __restrict__ wqh, unsigned short* __restrict__ wql,
        unsigned short* __restrict__ wkh, unsigned short* __restrict__ wkl,
        unsigned short* __restrict__ wvh) {
    int kc = blockIdx.x, a = blockIdx.y;
    const float* w = (a == 0) ? wq : (a == 1) ? wk : wv;
    __shared__ float tile[64 * 132];          // [kk 64][n 128], row pad->132
    int t = threadIdx.x;
#pragma unroll
    for (int j = 0; j < 8; ++j) {             // 64*128 floats, float4 loads
        int idx4 = t + j * 256;
        int kr = idx4 >> 5, n4 = idx4 & 31;
        *(float4_t*)(&tile[kr * 132 + n4 * 4]) =
            *(const float4_t*)(w + (size_t)(kc * 64 + kr) * DK + n4 * 4);
    }
    __syncthreads();
#pragma unroll
    for (int sw = 0; sw < 4; ++sw) {
        int cid = t + sw * 256;               // 0..1023
        int n = cid >> 3, sl = cid & 7;       // output 16B chunk (n, slot')
        int slot = sl ^ (n & 7);              // original k-slot
        short8_t hh, ll;
#pragma unroll
        for (int e = 0; e < 8; ++e) {
            float f = tile[(slot * 8 + e) * 132 + n];
            unsigned short h = f2bf(f);
            hh[e] = (short)h;
            ll[e] = (short)f2bf(f - bf2f(h));
        }
        size_t off = (size_t)kc * 8192 + n * 64 + sl * 8;   // shorts
        if (a == 0) { *(short8_t*)(wqh + off) = hh; *(short8_t*)(wql + off) = ll; }
        else if (a == 1) { *(short8_t*)(wkh + off) = hh; *(short8_t*)(wkl + off) = ll; }
        else { *(short8_t*)(wvh + off) = hh; }
    }
}

// ---------------------------------------------------------------------------
// K1 v3: QKV projection. BM=32, BK=64, BN=128. grid (256 mt, 3 grp), 4 waves.
// W via gload_lds from swizzled images; x converted in-reg, pad-72 LDS rows.
// Epilogue: Q row-major hi/lo; K hi/lo + V^T written in k2's tile images.
// ---------------------------------------------------------------------------
__global__ __launch_bounds__(256, 4) void k1_proj(
        const float* __restrict__ x,
        const float* __restrict__ bq, const float* __restrict__ bk,
        const float* __restrict__ bv,
        const unsigned short* __restrict__ wqh, const unsigned short* __restrict__ wql,
        const unsigned short* __restrict__ wkh, const unsigned short* __restrict__ wkl,
        const unsigned short* __restrict__ wvh,
        unsigned short* __restrict__ qh, unsigned short* __restrict__ ql,
        unsigned short* __restrict__ kht, unsigned short* __restrict__ klt,
        unsigned short* __restrict__ vtt) {
    int mt = blockIdx.x, grp = blockIdx.y;
    int rowbase = mt * 32;
    __shared__ __attribute__((aligned(16))) unsigned short xsh[32 * 72]; // pad 72
    __shared__ __attribute__((aligned(16))) unsigned short xsl[32 * 72];
    __shared__ __attribute__((aligned(16))) unsigned short wsh[128 * 64]; // swizzled image
    __shared__ __attribute__((aligned(16))) unsigned short wsl[128 * 64];

    int t = threadIdx.x, lane = t & 63, wid = t >> 6;
    int cc = lane & 15, g = lane >> 4;
    int wr = wid >> 1, wc = wid & 1;          // wave tile: rows wr*16, cols wc*64
    const bool split = (grp < 2);
    const unsigned short* bsh = (grp == 0) ? wqh : (grp == 1) ? wkh : wvh;
    const unsigned short* bsl = (grp == 0) ? wql : wkl;   // unused for V

    float4_t acc[4];
#pragma unroll
    for (int cf = 0; cf < 4; ++cf) acc[cf] = (float4_t){0.f, 0.f, 0.f, 0.f};

    int ar = t >> 3, ac8 = t & 7;             // A: row 0..31, col8 0..7

#pragma unroll 1
    for (int kc = 0; kc < 16; ++kc) {
        // ---- issue W gloads (async)
#pragma unroll
        for (int w = 0; w < 4; ++w) {
            gload16(bsh + (size_t)kc * 8192 + w * 2048 + t * 8,
                    (char*)wsh + w * 4096 + wid * 1024);
            if (split)
                gload16(bsl + (size_t)kc * 8192 + w * 2048 + t * 8,
                        (char*)wsl + w * 4096 + wid * 1024);
        }
        // ---- A: 8 f32 -> hi/lo bf16 -> LDS
        const float4_t* xp =
            (const float4_t*)(x + (size_t)(rowbase + ar) * DM + kc * 64 + ac8 * 8);
        float4_t xf0 = xp[0], xf1 = xp[1];
        short8_t hh, ll;
#pragma unroll
        for (int e = 0; e < 8; ++e) {
            float f = (e < 4) ? xf0[e] : xf1[e - 4];
            unsigned short h = f2bf(f);
            hh[e] = (short)h;
            if (split) ll[e] = (short)f2bf(f - bf2f(h));
        }
        *(short8_t*)(xsh + ar * 72 + ac8 * 8) = hh;
        if (split) *(short8_t*)(xsl + ar * 72 + ac8 * 8) = ll;
        __syncthreads();   // drains vmcnt (gloads landed) + lgkm

        // ---- compute: 2 k-slices of 32
#pragma unroll
        for (int s = 0; s < 2; ++s) {
            int ra = wr * 16 + cc;
            short8_t a_h = *(const short8_t*)(xsh + ra * 72 + s * 32 + g * 8);
            short8_t a_l;
            if (split) a_l = *(const short8_t*)(xsl + ra * 72 + s * 32 + g * 8);
#pragma unroll
            for (int cf = 0; cf < 4; ++cf) {
                int cb = wc * 64 + cf * 16 + cc;
                int slb = (s * 4 + g) ^ (cb & 7);
                short8_t b_h = *(const short8_t*)(wsh + cb * 64 + slb * 8);
                acc[cf] = MFMA(a_h, b_h, acc[cf], 0, 0, 0);
                if (split) {
                    short8_t b_l = *(const short8_t*)(wsl + cb * 64 + slb * 8);
                    acc[cf] = MFMA(a_h, b_l, acc[cf], 0, 0, 0);
                    acc[cf] = MFMA(a_l, b_h, acc[cf], 0, 0, 0);
                }
            }
        }
        __syncthreads();
    }

    // ---- epilogue
    const float* bias = (grp == 0) ? bq : (grp == 1) ? bk : bv;
#pragma unroll
    for (int cf = 0; cf < 4; ++cf) {
        int col = wc * 64 + cf * 16 + cc;
        float bv_ = bias[col];
#pragma unroll
        for (int i = 0; i < 4; ++i) {
            int m = rowbase + wr * 16 + g * 4 + i;
            float v = acc[cf][i] + bv_;
            unsigned short h = f2bf(v);
            if (grp == 0) {
                size_t o = (size_t)m * DK + col;
                qh[o] = h; ql[o] = f2bf(v - bf2f(h));
            } else if (grp == 1) {
                int r = m & 63;
                int slot = (col >> 3) ^ (r & 7);       // bit3 preserved
                size_t o = (size_t)(m >> 6) * 8192 + r * 128 + slot * 8 + (col & 7);
                kht[o] = h; klt[o] = f2bf(v - bf2f(h));
            } else {
                int c = m & 63;
                int slot = (c >> 3) ^ (col & 7);
                size_t o = (size_t)(m >> 6) * 8192 + col * 64 + slot * 8 + (c & 7);
                vtt[o] = h;
            }
        }
    }
}

// ---------------------------------------------------------------------------
// K2 v2: out_partial = cos(Q K^T) V. grid (MC, L/64, B), 4 waves.
// K/V staged by gload_lds from k1's swizzled tile images.
// ---------------------------------------------------------------------------
__global__ __launch_bounds__(256, 2) void k2_attn(
        const unsigned short* __restrict__ qh, const unsigned short* __restrict__ ql,
        const unsigned short* __restrict__ kht, const unsigned short* __restrict__ klt,
        const unsigned short* __restrict__ vtt, float* __restrict__ part) {
    int mc = blockIdx.x, qt = blockIdx.y, b = blockIdx.z;
    int t = threadIdx.x, lane = t & 63, wid = t >> 6;
    int cc = lane & 15, g = lane >> 4;

    __shared__ __attribute__((aligned(16))) unsigned short khs[64 * 128]; // swizzled image
    __shared__ __attribute__((aligned(16))) unsigned short kls[64 * 128];
    __shared__ __attribute__((aligned(16))) unsigned short vts[128 * 64]; // V^T image
    __shared__ __attribute__((aligned(16))) unsigned short ps[4][16 * 64];

    int q0 = b * LL + qt * 64 + wid * 16;
    short8_t qhf[4], qlf[4];
#pragma unroll
    for (int s = 0; s < 4; ++s) {
        size_t off = (size_t)(q0 + cc) * DK + s * 32 + g * 8;
        qhf[s] = *(const short8_t*)(qh + off);
        qlf[s] = *(const short8_t*)(ql + off);
    }
    float4_t o[8];
#pragma unroll
    for (int cf = 0; cf < 8; ++cf) o[cf] = (float4_t){0.f, 0.f, 0.f, 0.f};

#pragma unroll 1
    for (int mi = 0; mi < 8; ++mi) {
        int mtile = b * 32 + mc * 8 + mi;     // global 64-row m-tile index
        // ---- stage K hi/lo + V^T: 12 gloads, no VGPR roundtrip
#pragma unroll
        for (int w = 0; w < 4; ++w) {
            gload16(kht + (size_t)mtile * 8192 + w * 2048 + t * 8,
                    (char*)khs + w * 4096 + wid * 1024);
            gload16(klt + (size_t)mtile * 8192 + w * 2048 + t * 8,
                    (char*)kls + w * 4096 + wid * 1024);
            gload16(vtt + (size_t)mtile * 8192 + w * 2048 + t * 8,
                    (char*)vts + w * 4096 + wid * 1024);
        }
        __syncthreads();

        // ---- S = Q K^T (3-term split)
        float4_t sa[4];
#pragma unroll
        for (int cf = 0; cf < 4; ++cf) sa[cf] = (float4_t){0.f, 0.f, 0.f, 0.f};
#pragma unroll
        for (int cf = 0; cf < 4; ++cf) {
            int krow = cf * 16 + cc;
            int swz = (krow & 7) << 4;
#pragma unroll
            for (int s = 0; s < 4; ++s) {
                int off = (krow * 256 + (s * 32 + g * 8) * 2) ^ swz;
                short8_t bh = *(const short8_t*)((const char*)khs + off);
                short8_t bl = *(const short8_t*)((const char*)kls + off);
                sa[cf] = MFMA(qhf[s], bh, sa[cf], 0, 0, 0);
                sa[cf] = MFMA(qhf[s], bl, sa[cf], 0, 0, 0);
                sa[cf] = MFMA(qlf[s], bh, sa[cf], 0, 0, 0);
            }
        }
        // ---- P = cos(S) -> per-wave swizzled LDS
        char* pbase = (char*)&ps[wid][0];
#pragma unroll
        for (int cf = 0; cf < 4; ++cf) {
#pragma unroll
            for (int i = 0; i < 4; ++i) {
                float rv = sa[cf][i] * INV2PI;
                rv = rv - floorf(rv);
                float cvv;
                asm volatile("v_cos_f32 %0, %1" : "=v"(cvv) : "v"(rv));
                int rr = g * 4 + i, c = cf * 16 + cc;
                int off = (rr * 128 + c * 2) ^ ((rr & 7) << 4);
                *(unsigned short*)(pbase + off) = f2bf(cvv);
            }
        }
        // ---- out += P @ V
#pragma unroll
        for (int ksv = 0; ksv < 2; ++ksv) {
            int aoff = (cc * 128 + (ksv * 32 + g * 8) * 2) ^ ((cc & 7) << 4);
            short8_t pa = *(const short8_t*)(pbase + aoff);
#pragma unroll
            for (int cf = 0; cf < 8; ++cf) {
                int rv2 = cf * 16 + cc;
                int slv = (ksv * 4 + g) ^ (rv2 & 7);
                short8_t vb = *(const short8_t*)(vts + rv2 * 64 + slv * 8);
                o[cf] = MFMA(pa, vb, o[cf], 0, 0, 0);
            }
        }
        __syncthreads();
    }
    float* pp = part + ((size_t)(mc * BB + b) * LL + qt * 64 + wid * 16) * DK;
#pragma unroll
    for (int cf = 0; cf < 8; ++cf)
#pragma unroll
        for (int i = 0; i < 4; ++i)
            pp[(g * 4 + i) * DK + cf * 16 + cc] = o[cf][i];
}

// ---------------------------------------------------------------------------
// K3: out = sum of MC partials
// ---------------------------------------------------------------------------
__global__ __launch_bounds__(256) void k3_reduce(const float4_t* __restrict__ part,
                                                 float4_t* __restrict__ out) {
    constexpr int NT4 = MTOT * DK / 4;
    int idx = blockIdx.x * 256 + threadIdx.x;
    float4_t s = part[idx];
#pragma unroll
    for (int c = 1; c < MC; ++c) s += part[idx + (size_t)c * NT4];
    out[idx] = s;
}

// ---------------------------------------------------------------------------
extern "C" void kernel_launch(void* const* d_in, const int* in_sizes, int n_in,
                              void* d_out, int out_size, void* d_ws, size_t ws_size,
                              hipStream_t stream) {
    const float* x  = (const float*)d_in[0];
    const float* Wq = (const float*)d_in[1];
    const float* bq = (const float*)d_in[2];
    const float* Wk = (const float*)d_in[3];
    const float* bk = (const float*)d_in[4];
    const float* Wv = (const float*)d_in[5];
    const float* bv = (const float*)d_in[6];

    char* ws = (char*)d_ws;
    size_t off = 0;
    auto alloc = [&](size_t bytes) -> char* {
        char* p = ws + off;
        off += (bytes + 255) & ~(size_t)255;
        return p;
    };
    unsigned short* wqh = (unsigned short*)alloc((size_t)DK * DM * 2);
    unsigned short* wql = (unsigned short*)alloc((size_t)DK * DM * 2);
    unsigned short* wkh = (unsigned short*)alloc((size_t)DK * DM * 2);
    unsigned short* wkl = (unsigned short*)alloc((size_t)DK * DM * 2);
    unsigned short* wvh = (unsigned short*)alloc((size_t)DK * DM * 2);
    unsigned short* qh  = (unsigned short*)alloc((size_t)MTOT * DK * 2);
    unsigned short* ql  = (unsigned short*)alloc((size_t)MTOT * DK * 2);
    unsigned short* kht = (unsigned short*)alloc((size_t)MTOT * DK * 2);
    unsigned short* klt = (unsigned short*)alloc((size_t)MTOT * DK * 2);
    unsigned short* vtt = (unsigned short*)alloc((size_t)MTOT * DK * 2);
    float* part = (float*)alloc((size_t)MC * MTOT * DK * 4);

    k0_wsplit<<<dim3(16, 3), 256, 0, stream>>>(Wq, Wk, Wv, wqh, wql, wkh, wkl, wvh);
    k1_proj<<<dim3(MTOT / 32, 3), 256, 0, stream>>>(x, bq, bk, bv,
                                                    wqh, wql, wkh, wkl, wvh,
                                                    qh, ql, kht, klt, vtt);
    k2_attn<<<dim3(MC, LL / 64, BB), 256, 0, stream>>>(qh, ql, kht, klt, vtt, part);
    k3_reduce<<<(MTOT * DK / 4) / 256, 256, 0, stream>>>((const float4_t*)part,
                                                         (float4_t*)d_out);
}

// Round 5
// 70.543 us; speedup vs baseline: 1.2996x; 1.0596x over previous
//
#include <hip/hip_runtime.h>

typedef __attribute__((ext_vector_type(8))) short short8_t;      // 8 bf16
typedef __attribute__((ext_vector_type(4))) short short4_t;      // 4 bf16
typedef __attribute__((ext_vector_type(4))) float float4_t;      // MFMA C/D frag

#define MFMA __builtin_amdgcn_mfma_f32_16x16x32_bf16

constexpr int BB   = 4;
constexpr int LL   = 2048;
constexpr int DM   = 1024;
constexpr int DK   = 128;
constexpr int MTOT = BB * LL;     // 8192
constexpr int MC   = 4;
constexpr float INV2PI = 0.15915494309189535f;

// Fragment-major image layout (everywhere): [tile][g 4][cc 16][e 8] shorts.
// A 16B chunk holds 8 consecutive k's (e) for one n/row (cc). MFMA fragment
// reads are contiguous 16B at bank stride 4*cc -> 2-way only (free, m136).

__device__ __forceinline__ unsigned short f2bf(float f) {
    unsigned int u = __builtin_bit_cast(unsigned int, f);
    u += 0x7FFFu + ((u >> 16) & 1u);          // RNE
    return (unsigned short)(u >> 16);
}
__device__ __forceinline__ float bf2f(unsigned short h) {
    unsigned int u = ((unsigned int)h) << 16;
    return __builtin_bit_cast(float, u);
}
__device__ __forceinline__ void gload16(const void* g, void* l) {
    __builtin_amdgcn_global_load_lds(
        (const __attribute__((address_space(1))) void*)g,
        (__attribute__((address_space(3))) void*)l, 16, 0, 0);
}

// ---------------------------------------------------------------------------
// K0: W [1024 k][128 n] f32 -> fragment-major W^T images, hi/lo bf16.
// Image: [kc 32][cbt 8][g 4][cc 16][e 8]; element (n,k): kc=k>>5, g=(k>>3)&3,
// e=k&7, cbt=n>>4, cc=n&15.  grid (32 kc, 3 arr), block 256.
// ---------------------------------------------------------------------------
__global__ __launch_bounds__(256) void k0_wsplit(
        const float* __restrict__ wq, const float* __restrict__ wk,
        const float* __restrict__ wv,
        unsigned short* __restrict__ wqh, unsigned short* __restrict__ wql,
        unsigned short* __restrict__ wkh, unsigned short* __restrict__ wkl,
        unsigned short* __restrict__ wvh) {
    int kc = blockIdx.x, a = blockIdx.y;
    const float* w = (a == 0) ? wq : (a == 1) ? wk : wv;
    __shared__ float tile[32 * 132];          // [k 32][n 128] pad->132
    int t = threadIdx.x;
#pragma unroll
    for (int j = 0; j < 4; ++j) {
        int idx4 = t + j * 256;               // 1024 float4s
        int kr = idx4 >> 5, n4 = idx4 & 31;
        *(float4_t*)(&tile[kr * 132 + n4 * 4]) =
            *(const float4_t*)(w + (size_t)(kc * 32 + kr) * DK + n4 * 4);
    }
    __syncthreads();
#pragma unroll
    for (int sw = 0; sw < 2; ++sw) {
        int ch = t + sw * 256;                // 512 16B-chunks: (cbt*4+g)*16+cc
        int cbt = ch >> 6, g = (ch >> 4) & 3, cc = ch & 15;
        short8_t hh, ll;
#pragma unroll
        for (int e = 0; e < 8; ++e) {
            float f = tile[(g * 8 + e) * 132 + cbt * 16 + cc];
            unsigned short h = f2bf(f);
            hh[e] = (short)h;
            ll[e] = (short)f2bf(f - bf2f(h));
        }
        size_t off = (size_t)kc * 4096 + ch * 8;
        if (a == 0) { *(short8_t*)(wqh + off) = hh; *(short8_t*)(wql + off) = ll; }
        else if (a == 1) { *(short8_t*)(wkh + off) = hh; *(short8_t*)(wkl + off) = ll; }
        else { *(short8_t*)(wvh + off) = hh; }
    }
}

// ---------------------------------------------------------------------------
// K1: QKV projection. BM=32, BK=32, BN=128; grid (256 mt, 3 grp); 4 waves,
// wave tile 32r x 32c (rf=2, cf=2). 2-phase: stage(next) -> compute(cur) ->
// one barrier. LDS 40KB -> 4/CU cap, grid=3/CU. Outputs written as
// fragment-major images for k2 (Q,K hi/lo; V transposed).
// ---------------------------------------------------------------------------
__global__ __launch_bounds__(256, 3) void k1_proj(
        const float* __restrict__ x,
        const float* __restrict__ bq, const float* __restrict__ bk,
        const float* __restrict__ bv,
        const unsigned short* __restrict__ wqh, const unsigned short* __restrict__ wql,
        const unsigned short* __restrict__ wkh, const unsigned short* __restrict__ wkl,
        const unsigned short* __restrict__ wvh,
        unsigned short* __restrict__ qih, unsigned short* __restrict__ qil,
        unsigned short* __restrict__ kih, unsigned short* __restrict__ kil,
        unsigned short* __restrict__ vit) {
    int mt = blockIdx.x, grp = blockIdx.y;
    int rowbase = mt * 32;
    __shared__ __attribute__((aligned(16))) unsigned short wbh[2][4096]; // 8KB/buf
    __shared__ __attribute__((aligned(16))) unsigned short wbl[2][4096];
    __shared__ __attribute__((aligned(16))) unsigned short xbh[2][1024]; // 2KB/buf
    __shared__ __attribute__((aligned(16))) unsigned short xbl[2][1024];

    int t = threadIdx.x, lane = t & 63, wid = t >> 6;
    int cc = lane & 15, g = lane >> 4;
    const bool split = (grp < 2);
    const unsigned short* Wh = (grp == 0) ? wqh : (grp == 1) ? wkh : wvh;
    const unsigned short* Wl = (grp == 0) ? wql : wkl;

    float4_t acc[2][2];
#pragma unroll
    for (int rf = 0; rf < 2; ++rf)
#pragma unroll
        for (int cf = 0; cf < 2; ++cf) acc[rf][cf] = (float4_t){0.f, 0.f, 0.f, 0.f};

    // x staging map: t bits [7]=rt [6:3]=xc [2:1]=xg [0]=xh -> 128B/8thr rows
    int rt = t >> 7, xc = (t >> 3) & 15, xg = (t >> 1) & 3, xh_ = t & 1;
    const float* xsrc = x + (size_t)(rowbase + rt * 16 + xc) * DM + xg * 8 + xh_ * 4;
    int xoff = ((rt * 4 + xg) * 16 + xc) * 8 + xh_ * 4;   // shorts

    // ---- prologue: stage kc=0 into buf 0
    gload16(Wh + t * 8, (char*)wbh[0] + wid * 1024);
    gload16(Wh + 2048 + t * 8, (char*)wbh[0] + 4096 + wid * 1024);
    if (split) {
        gload16(Wl + t * 8, (char*)wbl[0] + wid * 1024);
        gload16(Wl + 2048 + t * 8, (char*)wbl[0] + 4096 + wid * 1024);
    }
    {
        float4_t xf = *(const float4_t*)(xsrc);
        short4_t hh, ll;
#pragma unroll
        for (int e = 0; e < 4; ++e) {
            unsigned short h = f2bf(xf[e]);
            hh[e] = (short)h;
            ll[e] = (short)f2bf(xf[e] - bf2f(h));
        }
        *(short4_t*)(xbh[0] + xoff) = hh;
        if (split) *(short4_t*)(xbl[0] + xoff) = ll;
    }
    __syncthreads();

#pragma unroll 1
    for (int kc = 0; kc < 32; ++kc) {
        int cb = kc & 1, nb = cb ^ 1;
        float4_t xf;
        bool more = (kc < 31);
        if (more) {
            // ---- issue next-step staging first (loads overlap compute)
            const unsigned short* Whn = Wh + (size_t)(kc + 1) * 4096;
            gload16(Whn + t * 8, (char*)wbh[nb] + wid * 1024);
            gload16(Whn + 2048 + t * 8, (char*)wbh[nb] + 4096 + wid * 1024);
            if (split) {
                const unsigned short* Wln = Wl + (size_t)(kc + 1) * 4096;
                gload16(Wln + t * 8, (char*)wbl[nb] + wid * 1024);
                gload16(Wln + 2048 + t * 8, (char*)wbl[nb] + 4096 + wid * 1024);
            }
            xf = *(const float4_t*)(xsrc + (kc + 1) * 32);
        }
        // ---- compute on cur buffer
        short8_t ah[2], al[2];
#pragma unroll
        for (int rf = 0; rf < 2; ++rf) {
            ah[rf] = *(const short8_t*)(xbh[cb] + ((rf * 4 + g) * 16 + cc) * 8);
            if (split)
                al[rf] = *(const short8_t*)(xbl[cb] + ((rf * 4 + g) * 16 + cc) * 8);
        }
#pragma unroll
        for (int cf = 0; cf < 2; ++cf) {
            int cbt = wid * 2 + cf;
            short8_t b_h = *(const short8_t*)(wbh[cb] + ((cbt * 4 + g) * 16 + cc) * 8);
#pragma unroll
            for (int rf = 0; rf < 2; ++rf)
                acc[rf][cf] = MFMA(ah[rf], b_h, acc[rf][cf], 0, 0, 0);
            if (split) {
                short8_t b_l = *(const short8_t*)(wbl[cb] + ((cbt * 4 + g) * 16 + cc) * 8);
#pragma unroll
                for (int rf = 0; rf < 2; ++rf) {
                    acc[rf][cf] = MFMA(ah[rf], b_l, acc[rf][cf], 0, 0, 0);
                    acc[rf][cf] = MFMA(al[rf], b_h, acc[rf][cf], 0, 0, 0);
                }
            }
        }
        // ---- convert next-x late (x-load waitcnt sits after MFMAs)
        if (more) {
            short4_t hh, ll;
#pragma unroll
            for (int e = 0; e < 4; ++e) {
                unsigned short h = f2bf(xf[e]);
                hh[e] = (short)h;
                ll[e] = (short)f2bf(xf[e] - bf2f(h));
            }
            *(short4_t*)(xbh[nb] + xoff) = hh;
            if (split) *(short4_t*)(xbl[nb] + xoff) = ll;
        }
        __syncthreads();   // drains gloads (in flight through whole compute)
    }

    // ---- epilogue: bias, split-cast, scatter into fragment-major images
    const float* bias = (grp == 0) ? bq : (grp == 1) ? bk : bv;
#pragma unroll
    for (int rf = 0; rf < 2; ++rf)
#pragma unroll
        for (int cf = 0; cf < 2; ++cf) {
            int c = wid * 32 + cf * 16 + cc;
            float bv_ = bias[c];
#pragma unroll
            for (int i = 0; i < 4; ++i) {
                int r = rowbase + rf * 16 + g * 4 + i;
                float v = acc[rf][cf][i] + bv_;
                unsigned short h = f2bf(v);
                if (grp == 0) {
                    size_t o = (size_t)(r >> 4) * 2048 + (c >> 5) * 512 +
                               ((c >> 3) & 3) * 128 + (r & 15) * 8 + (c & 7);
                    qih[o] = h; qil[o] = f2bf(v - bf2f(h));
                } else if (grp == 1) {
                    size_t o = (size_t)(r >> 5) * 4096 + ((r >> 4) & 1) * 2048 +
                               (c >> 5) * 512 + ((c >> 3) & 3) * 128 +
                               (r & 15) * 8 + (c & 7);
                    kih[o] = h; kil[o] = f2bf(v - bf2f(h));
                } else {
                    size_t o = (size_t)(r >> 5) * 4096 + (c >> 4) * 512 +
                               ((r >> 3) & 3) * 128 + (c & 15) * 8 + (r & 7);
                    vit[o] = h;
                }
            }
        }
}

// ---------------------------------------------------------------------------
// K2: out_partial = cos(Q K^T) V. grid (MC, L/64, B); 4 waves, 16 q-rows each.
// KVBLK=32, 16 steps, 2-phase double-buffered K/V images, 1 barrier/step.
// ---------------------------------------------------------------------------
__global__ __launch_bounds__(256, 2) void k2_attn(
        const unsigned short* __restrict__ qih, const unsigned short* __restrict__ qil,
        const unsigned short* __restrict__ kih, const unsigned short* __restrict__ kil,
        const unsigned short* __restrict__ vit, float* __restrict__ part) {
    int mc = blockIdx.x, qt = blockIdx.y, b = blockIdx.z;
    int t = threadIdx.x, lane = t & 63, wid = t >> 6;
    int cc = lane & 15, g = lane >> 4;

    __shared__ __attribute__((aligned(16))) unsigned short kbh[2][4096]; // 8KB/buf
    __shared__ __attribute__((aligned(16))) unsigned short kbl[2][4096];
    __shared__ __attribute__((aligned(16))) unsigned short vbt[2][4096];
    __shared__ __attribute__((aligned(16))) unsigned short ps[4][512];   // per-wave P

    int qrow = b * LL + qt * 64 + wid * 16;
    size_t qb = (size_t)(qrow >> 4) * 2048;
    short8_t qhf[4], qlf[4];
#pragma unroll
    for (int s = 0; s < 4; ++s) {
        size_t off = qb + s * 512 + g * 128 + cc * 8;
        qhf[s] = *(const short8_t*)(qih + off);
        qlf[s] = *(const short8_t*)(qil + off);
    }
    float4_t o[8];
#pragma unroll
    for (int cf = 0; cf < 8; ++cf) o[cf] = (float4_t){0.f, 0.f, 0.f, 0.f};

    int tbase = b * 64 + mc * 16;   // 32-row tile index base

    // prologue stage mi=0 -> buf0
    {
        const unsigned short* ks = kih + (size_t)tbase * 4096;
        const unsigned short* ls = kil + (size_t)tbase * 4096;
        const unsigned short* vs = vit + (size_t)tbase * 4096;
        gload16(ks + t * 8, (char*)kbh[0] + wid * 1024);
        gload16(ks + 2048 + t * 8, (char*)kbh[0] + 4096 + wid * 1024);
        gload16(ls + t * 8, (char*)kbl[0] + wid * 1024);
        gload16(ls + 2048 + t * 8, (char*)kbl[0] + 4096 + wid * 1024);
        gload16(vs + t * 8, (char*)vbt[0] + wid * 1024);
        gload16(vs + 2048 + t * 8, (char*)vbt[0] + 4096 + wid * 1024);
    }
    __syncthreads();

#pragma unroll 1
    for (int mi = 0; mi < 16; ++mi) {
        int cb = mi & 1, nb = cb ^ 1;
        if (mi < 15) {
            const unsigned short* ks = kih + (size_t)(tbase + mi + 1) * 4096;
            const unsigned short* ls = kil + (size_t)(tbase + mi + 1) * 4096;
            const unsigned short* vs = vit + (size_t)(tbase + mi + 1) * 4096;
            gload16(ks + t * 8, (char*)kbh[nb] + wid * 1024);
            gload16(ks + 2048 + t * 8, (char*)kbh[nb] + 4096 + wid * 1024);
            gload16(ls + t * 8, (char*)kbl[nb] + wid * 1024);
            gload16(ls + 2048 + t * 8, (char*)kbl[nb] + 4096 + wid * 1024);
            gload16(vs + t * 8, (char*)vbt[nb] + wid * 1024);
            gload16(vs + 2048 + t * 8, (char*)vbt[nb] + 4096 + wid * 1024);
        }
        // ---- S = Q K^T (3-term split), S-tile 16q x 32m
        float4_t sa[2];
#pragma unroll
        for (int cf = 0; cf < 2; ++cf) sa[cf] = (float4_t){0.f, 0.f, 0.f, 0.f};
#pragma unroll
        for (int cf = 0; cf < 2; ++cf)
#pragma unroll
            for (int s = 0; s < 4; ++s) {
                int off = cf * 2048 + s * 512 + g * 128 + cc * 8;
                short8_t bh = *(const short8_t*)(kbh[cb] + off);
                short8_t bl = *(const short8_t*)(kbl[cb] + off);
                sa[cf] = MFMA(qhf[s], bh, sa[cf], 0, 0, 0);
                sa[cf] = MFMA(qhf[s], bl, sa[cf], 0, 0, 0);
                sa[cf] = MFMA(qlf[s], bh, sa[cf], 0, 0, 0);
            }
        // ---- P = cos(S) -> per-wave fragment-major LDS [g4][cc16][e8]
#pragma unroll
        for (int cf = 0; cf < 2; ++cf)
#pragma unroll
            for (int i = 0; i < 4; ++i) {
                float rv = sa[cf][i] * INV2PI;
                rv = rv - floorf(rv);
                float cv;
                asm volatile("v_cos_f32 %0, %1" : "=v"(cv) : "v"(rv));
                int m = cf * 16 + cc, q = g * 4 + i;
                ps[wid][(m >> 3) * 128 + q * 8 + (m & 7)] = f2bf(cv);
            }
        // ---- out += P @ V
        short8_t pa = *(const short8_t*)(&ps[wid][g * 128 + cc * 8]);
#pragma unroll
        for (int cf = 0; cf < 8; ++cf) {
            short8_t vb = *(const short8_t*)(vbt[cb] + cf * 512 + g * 128 + cc * 8);
            o[cf] = MFMA(pa, vb, o[cf], 0, 0, 0);
        }
        __syncthreads();
    }
    float* pp = part + ((size_t)(mc * BB + b) * LL + qt * 64 + wid * 16) * DK;
#pragma unroll
    for (int cf = 0; cf < 8; ++cf)
#pragma unroll
        for (int i = 0; i < 4; ++i)
            pp[(g * 4 + i) * DK + cf * 16 + cc] = o[cf][i];
}

// ---------------------------------------------------------------------------
// K3: out = sum of MC partials
// ---------------------------------------------------------------------------
__global__ __launch_bounds__(256) void k3_reduce(const float4_t* __restrict__ part,
                                                 float4_t* __restrict__ out) {
    constexpr int NT4 = MTOT * DK / 4;
    int idx = blockIdx.x * 256 + threadIdx.x;
    float4_t s = part[idx];
#pragma unroll
    for (int c = 1; c < MC; ++c) s += part[idx + (size_t)c * NT4];
    out[idx] = s;
}

// ---------------------------------------------------------------------------
extern "C" void kernel_launch(void* const* d_in, const int* in_sizes, int n_in,
                              void* d_out, int out_size, void* d_ws, size_t ws_size,
                              hipStream_t stream) {
    const float* x  = (const float*)d_in[0];
    const float* Wq = (const float*)d_in[1];
    const float* bq = (const float*)d_in[2];
    const float* Wk = (const float*)d_in[3];
    const float* bk = (const float*)d_in[4];
    const float* Wv = (const float*)d_in[5];
    const float* bv = (const float*)d_in[6];

    char* ws = (char*)d_ws;
    size_t off = 0;
    auto alloc = [&](size_t bytes) -> char* {
        char* p = ws + off;
        off += (bytes + 255) & ~(size_t)255;
        return p;
    };
    unsigned short* wqh = (unsigned short*)alloc((size_t)DK * DM * 2);
    unsigned short* wql = (unsigned short*)alloc((size_t)DK * DM * 2);
    unsigned short* wkh = (unsigned short*)alloc((size_t)DK * DM * 2);
    unsigned short* wkl = (unsigned short*)alloc((size_t)DK * DM * 2);
    unsigned short* wvh = (unsigned short*)alloc((size_t)DK * DM * 2);
    unsigned short* qih = (unsigned short*)alloc((size_t)MTOT * DK * 2);
    unsigned short* qil = (unsigned short*)alloc((size_t)MTOT * DK * 2);
    unsigned short* kih = (unsigned short*)alloc((size_t)MTOT * DK * 2);
    unsigned short* kil = (unsigned short*)alloc((size_t)MTOT * DK * 2);
    unsigned short* vit = (unsigned short*)alloc((size_t)MTOT * DK * 2);
    float* part = (float*)alloc((size_t)MC * MTOT * DK * 4);

    k0_wsplit<<<dim3(32, 3), 256, 0, stream>>>(Wq, Wk, Wv, wqh, wql, wkh, wkl, wvh);
    k1_proj<<<dim3(MTOT / 32, 3), 256, 0, stream>>>(x, bq, bk, bv,
                                                    wqh, wql, wkh, wkl, wvh,
                                                    qih, qil, kih, kil, vit);
    k2_attn<<<dim3(MC, LL / 64, BB), 256, 0, stream>>>(qih, qil, kih, kil, vit, part);
    k3_reduce<<<(MTOT * DK / 4) / 256, 256, 0, stream>>>((const float4_t*)part,
                                                         (float4_t*)d_out);
}